// Round 7
// baseline (289.379 us; speedup 1.0000x reference)
//
#include <hip/hip_runtime.h>

#define B_ 4096
#define C_ 128
#define D_ 768
#define NT 1024
#define NW (NT/64)                  // 16 waves
#define M_MAX 96
#define P_MAX (M_MAX*(M_MAX-1)/2)   // 4560
#define CK 128
#define NCH (D_/CK)                 // 6
#define SROW 132                    // floats; bank(row r) = 4r mod 32 -> consecutive rows spread 8 banks
#define TILE_F (M_MAX*SROW)         // 12672 floats per buffer
#define LM2 2                       // max 2x2 units per thread: U <= 1225 < 2*NT
#define RC 127                      // row code meaning "cvec"
#define SPT ((M_MAX*(CK/4) + NT - 1)/NT)    // 3 staging float4s per thread

__device__ __forceinline__ float wave_red(float v){
#pragma unroll
  for (int o = 32; o > 0; o >>= 1) v += __shfl_down(v, o, 64);
  return v;
}
__device__ __forceinline__ float wave_min(float v){
#pragma unroll
  for (int o = 32; o > 0; o >>= 1) v = fminf(v, __shfl_down(v, o, 64));
  return v;
}
__device__ __forceinline__ float wave_max(float v){
#pragma unroll
  for (int o = 32; o > 0; o >>= 1) v = fmaxf(v, __shfl_down(v, o, 64));
  return v;
}
__device__ __forceinline__ float clamp1(float x){ return fminf(fmaxf(x, -1.f), 1.f); }
__device__ __forceinline__ unsigned rotl32(unsigned x, int r){ return (x << r) | (x >> (32 - r)); }
__device__ __forceinline__ float dot4(float4 a, float4 b){
  return fmaf(a.x, b.x, fmaf(a.y, b.y, fmaf(a.z, b.z, a.w * b.w)));
}

// jax.random.uniform(jax.random.key(1),(B,B)) element n: Threefry-2x32 key (0,1),
// counters split in halves. Bit-exact (verified: absmax 0.0 across all rounds).
__device__ float rand_ij(unsigned n){
  const unsigned half = (unsigned)B_ * (unsigned)B_ / 2u;
  unsigned c0, c1; bool hi;
  if (n < half){ c0 = n; c1 = n + half; hi = false; }
  else         { c0 = n - half; c1 = n; hi = true; }
  const unsigned K0 = 0u, K1 = 1u, K2 = 0x1BD11BDBu;
  unsigned x0 = c0 + K0, x1 = c1 + K1;
#define TFR(r) { x0 += x1; x1 = rotl32(x1, (r)); x1 ^= x0; }
  TFR(13) TFR(15) TFR(26) TFR(6)  x0 += K1; x1 += K2 + 1u;
  TFR(17) TFR(29) TFR(16) TFR(24) x0 += K2; x1 += K0 + 2u;
  TFR(13) TFR(15) TFR(26) TFR(6)  x0 += K0; x1 += K1 + 3u;
  TFR(17) TFR(29) TFR(16) TFR(24) x0 += K1; x1 += K2 + 4u;
  TFR(13) TFR(15) TFR(26) TFR(6)  x0 += K2; x1 += K0 + 5u;
#undef TFR
  unsigned bits = hi ? x1 : x0;
  return __uint_as_float((bits >> 9) | 0x3F800000u) - 1.0f;
}

// p -> (a,b), a<b<m, row-major upper-tri. before(a) = a*(2m-1-a)/2.
__device__ __forceinline__ void decode_pair(int p, int m, int* a_, int* b_){
  float fm = (float)(2*m - 1);
  int a = (int)((fm - sqrtf(fm*fm - 8.0f*(float)p)) * 0.5f);
  a = max(0, min(a, m - 2));
  while (a > 0 && (a*(2*m - 1 - a))/2 > p) --a;
  while (((a + 1)*(2*m - 2 - a))/2 <= p) ++a;
  *a_ = a;
  *b_ = a + 1 + (p - (a*(2*m - 1 - a))/2);
}

// ---- slow-path helpers (unreachable: all classes m<=96; insurance only) ----
__device__ float dotg(const float* x, const float* y){
  float s = 0.f;
  for (int k = 0; k < D_; ++k) s = fmaf(x[k], y[k], s);
  return s;
}
__device__ float S_pair_g(const float* feat, int ga, int gb){
  const float* ra = feat + (size_t)ga * D_;
  const float* rb = feat + (size_t)gb * D_;
  float d = dotg(ra, rb);
  float na = 1.f / fmaxf(sqrtf(dotg(ra, ra)), 1e-12f);
  float nb = 1.f / fmaxf(sqrtf(dotg(rb, rb)), 1e-12f);
  return d * na * nb;
}

// ==== MAIN kernel: unchanged from R6 (verified 80 us, absmax 0.0) ====
__global__ __launch_bounds__(NT) void k_all(
    const float* __restrict__ feat, const float* __restrict__ cent,
    const int* __restrict__ labels,
    float* __restrict__ lossv, float* __restrict__ wv,
    unsigned* __restrict__ flags, float* __restrict__ out)
{
  const int c = blockIdx.x;
  const int tid = threadIdx.x;
  const int wid = tid >> 6, lane = tid & 63;

  __shared__ int   gid_s[M_MAX];
  __shared__ int   mcount;
  __shared__ __align__(16) float tile[2 * TILE_F];     // 101376 B, double-buffered
  __shared__ __align__(16) float cvec[2][CK];
  float*          Sl     = tile;
  float*          Pd     = tile + P_MAX;
  unsigned short* fidx_s = (unsigned short*)(tile + 2 * P_MAX);
  __shared__ float selfs[M_MAX];
  __shared__ float ecs[M_MAX];
  __shared__ float cn_sh;
  __shared__ int   wcnt[NW * 64];
  __shared__ float mnb[NW], mxb[NW];
  __shared__ float lo_sh, sF_sh;
  __shared__ int   B0_sh, ex_sh, B1_sh;
  __shared__ float thr_sh;
  __shared__ float redbuf[2 * NW];
  __shared__ int   last_sh;

  if (tid == 0) mcount = 0;
  __syncthreads();
  {
    const int4* lab4 = (const int4*)labels;
    for (int i = tid; i < B_ / 4; i += NT){
      int4 L = lab4[i];
      int base = i << 2;
      if (L.x == c){ int p = atomicAdd(&mcount, 1); if (p < M_MAX) gid_s[p] = base; }
      if (L.y == c){ int p = atomicAdd(&mcount, 1); if (p < M_MAX) gid_s[p] = base + 1; }
      if (L.z == c){ int p = atomicAdd(&mcount, 1); if (p < M_MAX) gid_s[p] = base + 2; }
      if (L.w == c){ int p = atomicAdd(&mcount, 1); if (p < M_MAX) gid_s[p] = base + 3; }
    }
  }
  __syncthreads();
  const int m = mcount;

  float lloss = 0.f, lw = 0.f;

  if (m >= 2 && m <= M_MAX){
    const int P = m * (m - 1) / 2;
    const int k0 = (P - 1) >> 1;
    const float wc = (float)m;
    const int nst = m * (CK / 4);

    const int h    = (m + 1) >> 1;
    const int Upair = h * (h + 1) / 2;
    const int hec  = (m + 2) >> 1;
    const int U    = Upair + hec;

    int c0[LM2], c1[LM2], c2[LM2], c3[LM2];
    int tAv[LM2], tBv[LM2];
    float acc[LM2][4];
    int nlay = 0;
#pragma unroll
    for (int t = 0; t < LM2; ++t){
      acc[t][0] = acc[t][1] = acc[t][2] = acc[t][3] = 0.f;
      c0[t] = c1[t] = c2[t] = c3[t] = 0; tAv[t] = 0; tBv[t] = -3;
      int u = tid + t * NT;
      if (u < U){
        nlay = t + 1;
        if (u < Upair){
          int ta = 0;
          while ((ta + 1) * h - ((ta + 1) * ta) / 2 <= u) ++ta;
          int tb = ta + (u - (ta * h - (ta * (ta - 1)) / 2));
          c0[t] = ta; c1[t] = ta + h; c2[t] = tb; c3[t] = tb + h;
          tAv[t] = ta; tBv[t] = tb;
        } else {
          int g = u - Upair;
          int l1 = g + hec;
          c0[t] = g;
          c1[t] = (l1 == m) ? RC : ((l1 < m) ? l1 : 0);
          c2[t] = RC; c3[t] = RC;
          tAv[t] = g; tBv[t] = -1;
        }
      }
    }

    float4 pf[SPT];
    float4 cpf;
#pragma unroll
    for (int k = 0; k < SPT; ++k){
      int e = tid + k * NT;
      if (e < nst){
        int r = e >> 5, j = e & 31;
        pf[k] = ((const float4*)(feat + (size_t)gid_s[r] * D_))[j];
      }
    }
    if (tid < CK/4) cpf = ((const float4*)(cent + (size_t)c * D_))[tid];
#pragma unroll
    for (int k = 0; k < SPT; ++k){
      int e = tid + k * NT;
      if (e < nst){
        int r = e >> 5, j = e & 31;
        ((float4*)&tile[r * SROW])[j] = pf[k];
      }
    }
    if (tid < CK/4) ((float4*)cvec[0])[tid] = cpf;
    __syncthreads();

    for (int ch = 0; ch < NCH; ++ch){
      const int cur = ch & 1;
      if (ch + 1 < NCH){
        const int d0 = (ch + 1) * CK;
#pragma unroll
        for (int k = 0; k < SPT; ++k){
          int e = tid + k * NT;
          if (e < nst){
            int r = e >> 5, j = e & 31;
            pf[k] = ((const float4*)(feat + (size_t)gid_s[r] * D_ + d0))[j];
          }
        }
        if (tid < CK/4) cpf = ((const float4*)(cent + (size_t)c * D_ + d0))[tid];
      }
      {
        const float* tl = tile + cur * TILE_F;
        const float4* cv4 = (const float4*)cvec[cur];
#pragma unroll
        for (int t = 0; t < LM2; ++t){
          if (t < nlay){
            const float4* A0 = (c0[t] == RC) ? cv4 : (const float4*)&tl[c0[t] * SROW];
            const float4* A1 = (c1[t] == RC) ? cv4 : (const float4*)&tl[c1[t] * SROW];
            const float4* Bp0 = (c2[t] == RC) ? cv4 : (const float4*)&tl[c2[t] * SROW];
            const float4* Bp1 = (c3[t] == RC) ? cv4 : (const float4*)&tl[c3[t] * SROW];
            float s00 = 0.f, s01 = 0.f, s10 = 0.f, s11 = 0.f;
#pragma unroll 8
            for (int j = 0; j < CK/4; ++j){
              float4 a0 = A0[j], a1 = A1[j], b0 = Bp0[j], b1 = Bp1[j];
              s00 += dot4(a0, b0); s01 += dot4(a0, b1);
              s10 += dot4(a1, b0); s11 += dot4(a1, b1);
            }
            acc[t][0] += s00; acc[t][1] += s01;
            acc[t][2] += s10; acc[t][3] += s11;
          }
        }
      }
      if (ch + 1 < NCH){
        float* tn = tile + (cur ^ 1) * TILE_F;
#pragma unroll
        for (int k = 0; k < SPT; ++k){
          int e = tid + k * NT;
          if (e < nst){
            int r = e >> 5, j = e & 31;
            ((float4*)&tn[r * SROW])[j] = pf[k];
          }
        }
        if (tid < CK/4) ((float4*)cvec[cur ^ 1])[tid] = cpf;
      }
      __syncthreads();
    }

#pragma unroll
    for (int t = 0; t < LM2; ++t){
      if (t < nlay){
        if (tBv[t] == -1){
          int g = tAv[t], l1 = g + hec;
          ecs[g] = acc[t][0];
          if (l1 == m) cn_sh = acc[t][2];
          else if (l1 < m) ecs[l1] = acc[t][2];
        } else if (tBv[t] >= 0){
          const int ta = tAv[t], tb = tBv[t];
          const int a1 = ta + h, b1 = tb + h;
          if (ta == tb){
            if (ta < m) selfs[ta] = acc[t][0];
            if (a1 < m) selfs[a1] = acc[t][3];
            if (b1 < m) Sl[(ta*(2*m - 1 - ta))/2 + (b1 - ta - 1)] = acc[t][1];
          } else {
            Sl[(ta*(2*m - 1 - ta))/2 + (tb - ta - 1)] = acc[t][0];
            if (b1 < m) Sl[(ta*(2*m - 1 - ta))/2 + (b1 - ta - 1)] = acc[t][1];
            if (a1 < m) Sl[(tb*(2*m - 1 - tb))/2 + (a1 - tb - 1)] = acc[t][2];
            if (a1 < m && b1 < m) Sl[(a1*(2*m - 1 - a1))/2 + (b1 - a1 - 1)] = acc[t][3];
          }
        }
      }
    }
    __syncthreads();
    if (tid < m){
      float rn  = 1.f / fmaxf(sqrtf(selfs[tid]), 1e-12f);
      float cno = 1.f / fmaxf(sqrtf(cn_sh), 1e-12f);
      selfs[tid] = rn;
      ecs[tid] = ecs[tid] * rn * cno;
    }
    __syncthreads();

    float pmn = 1e30f, pmx = -1e30f;
    for (int p = tid; p < P; p += NT){
      int a, b; decode_pair(p, m, &a, &b);
      float S = Sl[p] * selfs[a] * selfs[b];
      float pd = 1.f - clamp1(S);
      Sl[p] = S; Pd[p] = pd;
      pmn = fminf(pmn, pd); pmx = fmaxf(pmx, pd);
    }
    pmn = wave_min(pmn); pmx = wave_max(pmx);
    if (lane == 0){ mnb[wid] = pmn; mxb[wid] = pmx; }
    __syncthreads();
    if (tid == 0){
      float mn = mnb[0], mx = mxb[0];
#pragma unroll
      for (int i = 1; i < NW; ++i){ mn = fminf(mn, mnb[i]); mx = fmaxf(mx, mxb[i]); }
      lo_sh = mn;
      sF_sh = 4096.f / fmaxf(mx - mn, 1e-20f);
    }
    __syncthreads();
    const float lo = lo_sh, sF = sF_sh;

    const int nch = (P + NT - 1) / NT;
    int cl = 0;
    for (int t = 0; t < nch; ++t){
      int p = tid + t * NT;
      int bkt = -1;
      if (p < P){
        int f = (int)((Pd[p] - lo) * sF);
        f = max(0, min(4095, f));
        fidx_s[p] = (unsigned short)f;
        bkt = f >> 6;
      }
#pragma unroll
      for (int k = 0; k < 64; ++k){
        unsigned long long msk = __ballot(bkt == k);
        if (lane == k) cl += __popcll(msk);
      }
    }
    wcnt[wid*64 + lane] = cl;
    __syncthreads();
    if (tid < 64){
      int tot = 0;
#pragma unroll
      for (int w = 0; w < NW; ++w) tot += wcnt[w*64 + tid];
      int inc = tot;
#pragma unroll
      for (int o = 1; o < 64; o <<= 1){
        int v = __shfl_up(inc, o, 64);
        if (tid >= o) inc += v;
      }
      int excl = inc - tot;
      if (excl <= k0 && k0 < inc){ B0_sh = tid; ex_sh = excl; }
    }
    __syncthreads();
    const int Bsel0 = B0_sh;
    const int kt = k0 - ex_sh;
    cl = 0;
    for (int t = 0; t < nch; ++t){
      int p = tid + t * NT;
      int bkt = -1;
      if (p < P){
        int f = fidx_s[p];
        if ((f >> 6) == Bsel0) bkt = f & 63;
      }
#pragma unroll
      for (int k = 0; k < 64; ++k){
        unsigned long long msk = __ballot(bkt == k);
        if (lane == k) cl += __popcll(msk);
      }
    }
    wcnt[wid*64 + lane] = cl;
    __syncthreads();
    if (tid < 64){
      int tot = 0;
#pragma unroll
      for (int w = 0; w < NW; ++w) tot += wcnt[w*64 + tid];
      int inc = tot;
#pragma unroll
      for (int o = 1; o < 64; o <<= 1){
        int v = __shfl_up(inc, o, 64);
        if (tid >= o) inc += v;
      }
      int excl = inc - tot;
      if (excl <= kt && kt < inc) B1_sh = tid;
    }
    __syncthreads();
    const int fsel = (Bsel0 << 6) | B1_sh;

    {
      const float4* Pd4 = (const float4*)Pd;
      const int nq4 = P >> 2;
      for (int p = tid; p < P; p += NT){
        if (fidx_s[p] == (unsigned short)fsel){
          const float pdp = Pd[p];
          int lt = 0, eq = 0;
#pragma unroll 4
          for (int q4 = 0; q4 < nq4; ++q4){
            float4 v = Pd4[q4];
            lt += (v.x < pdp) + (v.y < pdp) + (v.z < pdp) + (v.w < pdp);
            eq += (v.x == pdp) + (v.y == pdp) + (v.z == pdp) + (v.w == pdp);
          }
          for (int q = nq4 << 2; q < P; ++q){
            float pdq = Pd[q];
            lt += (pdq < pdp); eq += (pdq == pdp);
          }
          if (lt <= k0 && k0 < lt + eq) thr_sh = pdp;
        }
      }
    }
    __syncthreads();
    const float thr = thr_sh;

    for (int p = tid; p < P; p += NT){
      float pd = Pd[p];
      if (pd > thr){
        float S = Sl[p];
        int a, b; decode_pair(p, m, &a, &b);
        int ga = gid_s[a], gb = gid_s[b];
        float ea = ecs[a], eb = ecs[b];
        int i, j; float eci, ecj;
        if (ga < gb){ i = ga; j = gb; eci = ea; ecj = eb; }
        else        { i = gb; j = ga; eci = eb; ecj = ea; }
        float r = rand_ij((unsigned)i * (unsigned)B_ + (unsigned)j);
        float omr = 1.f - r;
        float n2 = r * r + omr * omr + 2.f * r * omr * S;
        float nrm = fmaxf(sqrtf(fmaxf(n2, 0.f)), 1e-12f);
        float dt = clamp1((r * eci + omr * ecj) / nrm);
        lloss += wc * (1.f - dt);
        lw += wc;
      }
    }
  } else if (m > M_MAX){
    int* mem = (int*)Sl;
    if (tid == 0) B0_sh = 0;
    __syncthreads();
    for (int i = tid; i < B_; i += NT)
      if (labels[i] == c){ int p = atomicAdd(&B0_sh, 1); mem[p] = i; }
    __syncthreads();
    const int P = m * (m - 1) / 2;
    const int k0 = (P - 1) >> 1;
    const float wc = (float)m;
    const float* cc = cent + (size_t)c * D_;
    const float cno = 1.f / fmaxf(sqrtf(dotg(cc, cc)), 1e-12f);
    for (int p = tid; p < P; p += NT){
      int a, b; decode_pair(p, m, &a, &b);
      float pdp = 1.f - clamp1(S_pair_g(feat, mem[a], mem[b]));
      int lt = 0, eq = 0;
      for (int q = 0; q < P; ++q){
        int a2, b2; decode_pair(q, m, &a2, &b2);
        float pdq = 1.f - clamp1(S_pair_g(feat, mem[a2], mem[b2]));
        lt += (pdq < pdp); eq += (pdq == pdp);
      }
      if (lt <= k0 && k0 < lt + eq) thr_sh = pdp;
    }
    __syncthreads();
    const float thr = thr_sh;
    for (int p = tid; p < P; p += NT){
      int a, b; decode_pair(p, m, &a, &b);
      int ga = mem[a], gb = mem[b];
      float S = S_pair_g(feat, ga, gb);
      float pd = 1.f - clamp1(S);
      if (pd > thr){
        if (ga > gb){ int t2 = ga; ga = gb; gb = t2; }
        const float* ra = feat + (size_t)ga * D_;
        const float* rb = feat + (size_t)gb * D_;
        float eci = dotg(ra, cc) / fmaxf(sqrtf(dotg(ra, ra)), 1e-12f) * cno;
        float ecj = dotg(rb, cc) / fmaxf(sqrtf(dotg(rb, rb)), 1e-12f) * cno;
        float r = rand_ij((unsigned)ga * (unsigned)B_ + (unsigned)gb);
        float omr = 1.f - r;
        float n2 = r * r + omr * omr + 2.f * r * omr * S;
        float nrm = fmaxf(sqrtf(fmaxf(n2, 0.f)), 1e-12f);
        float dt = clamp1((r * eci + omr * ecj) / nrm);
        lloss += wc * (1.f - dt);
        lw += wc;
      }
    }
  }

  lloss = wave_red(lloss); lw = wave_red(lw);
  if (lane == 0){ redbuf[wid] = lloss; redbuf[NW + wid] = lw; }
  __syncthreads();
  if (tid == 0){
    float tl = 0.f, tw = 0.f;
#pragma unroll
    for (int i = 0; i < NW; ++i){ tl += redbuf[i]; tw += redbuf[NW + i]; }
    __hip_atomic_store(&lossv[c], tl, __ATOMIC_RELAXED, __HIP_MEMORY_SCOPE_AGENT);
    __hip_atomic_store(&wv[c],   tw, __ATOMIC_RELAXED, __HIP_MEMORY_SCOPE_AGENT);
    unsigned old = __hip_atomic_fetch_add(&flags[0], 1u, __ATOMIC_ACQ_REL,
                                          __HIP_MEMORY_SCOPE_AGENT);
    last_sh = ((old & 127u) == 127u) ? 1 : 0;
  }
  __syncthreads();
  if (last_sh){
    float lv = 0.f, wvv = 0.f;
    if (tid < C_){
      lv  = __hip_atomic_load(&lossv[tid], __ATOMIC_RELAXED, __HIP_MEMORY_SCOPE_AGENT);
      wvv = __hip_atomic_load(&wv[tid],   __ATOMIC_RELAXED, __HIP_MEMORY_SCOPE_AGENT);
    }
    lv = wave_red(lv); wvv = wave_red(wvv);
    if (lane == 0){ redbuf[wid] = lv; redbuf[NW + wid] = wvv; }
    __syncthreads();
    if (tid == 0){
      float l = redbuf[0] + redbuf[1];
      float w = redbuf[NW] + redbuf[NW + 1];
      out[0] = (w > 0.f) ? (l / w) : 0.f;
    }
  }
}

// ==== DIAG 1: phase A + 3x {staging + gram chunk loop}. No global writes.
// asm keepalives prevent DCE (rule #17); opaque zero offset defeats
// cross-rep global-load CSE. Duration ~= A + 3*S. ====
__global__ __launch_bounds__(NT) void k_diag_gram(
    const float* __restrict__ feat, const float* __restrict__ cent,
    const int* __restrict__ labels)
{
  const int c = blockIdx.x;
  const int tid = threadIdx.x;

  __shared__ int   gid_s[M_MAX];
  __shared__ int   mcount;
  __shared__ __align__(16) float tile[2 * TILE_F];
  __shared__ __align__(16) float cvec[2][CK];

  if (tid == 0) mcount = 0;
  __syncthreads();
  {
    const int4* lab4 = (const int4*)labels;
    for (int i = tid; i < B_ / 4; i += NT){
      int4 L = lab4[i];
      int base = i << 2;
      if (L.x == c){ int p = atomicAdd(&mcount, 1); if (p < M_MAX) gid_s[p] = base; }
      if (L.y == c){ int p = atomicAdd(&mcount, 1); if (p < M_MAX) gid_s[p] = base + 1; }
      if (L.z == c){ int p = atomicAdd(&mcount, 1); if (p < M_MAX) gid_s[p] = base + 2; }
      if (L.w == c){ int p = atomicAdd(&mcount, 1); if (p < M_MAX) gid_s[p] = base + 3; }
    }
  }
  __syncthreads();
  const int m = mcount;

  if (m >= 2 && m <= M_MAX){
    const int nst = m * (CK / 4);
    const int h    = (m + 1) >> 1;
    const int Upair = h * (h + 1) / 2;
    const int hec  = (m + 2) >> 1;
    const int U    = Upair + hec;

    int c0[LM2], c1[LM2], c2[LM2], c3[LM2];
    int nlay = 0;
#pragma unroll
    for (int t = 0; t < LM2; ++t){
      c0[t] = c1[t] = c2[t] = c3[t] = 0;
      int u = tid + t * NT;
      if (u < U){
        nlay = t + 1;
        if (u < Upair){
          int ta = 0;
          while ((ta + 1) * h - ((ta + 1) * ta) / 2 <= u) ++ta;
          int tb = ta + (u - (ta * h - (ta * (ta - 1)) / 2));
          c0[t] = ta; c1[t] = ta + h; c2[t] = tb; c3[t] = tb + h;
        } else {
          int g = u - Upair;
          int l1 = g + hec;
          c0[t] = g;
          c1[t] = (l1 == m) ? RC : ((l1 < m) ? l1 : 0);
          c2[t] = RC; c3[t] = RC;
        }
      }
    }

    for (int rep = 0; rep < 3; ++rep){
      int zo = 0;
      asm volatile("" : "+v"(zo));          // opaque zero: loads can't CSE across reps
      float acc[LM2][4];
#pragma unroll
      for (int t = 0; t < LM2; ++t) acc[t][0] = acc[t][1] = acc[t][2] = acc[t][3] = 0.f;

      float4 pf[SPT];
      float4 cpf;
#pragma unroll
      for (int k = 0; k < SPT; ++k){
        int e = tid + k * NT;
        if (e < nst){
          int r = e >> 5, j = (e & 31) + zo;
          pf[k] = ((const float4*)(feat + (size_t)gid_s[r] * D_))[j];
        }
      }
      if (tid < CK/4) cpf = ((const float4*)(cent + (size_t)c * D_))[tid + zo];
#pragma unroll
      for (int k = 0; k < SPT; ++k){
        int e = tid + k * NT;
        if (e < nst){
          int r = e >> 5, j = e & 31;
          ((float4*)&tile[r * SROW])[j] = pf[k];
        }
      }
      if (tid < CK/4) ((float4*)cvec[0])[tid] = cpf;
      __syncthreads();

      for (int ch = 0; ch < NCH; ++ch){
        const int cur = ch & 1;
        if (ch + 1 < NCH){
          const int d0 = (ch + 1) * CK;
#pragma unroll
          for (int k = 0; k < SPT; ++k){
            int e = tid + k * NT;
            if (e < nst){
              int r = e >> 5, j = (e & 31) + zo;
              pf[k] = ((const float4*)(feat + (size_t)gid_s[r] * D_ + d0))[j];
            }
          }
          if (tid < CK/4) cpf = ((const float4*)(cent + (size_t)c * D_ + d0))[tid + zo];
        }
        {
          const float* tl = tile + cur * TILE_F;
          const float4* cv4 = (const float4*)cvec[cur];
#pragma unroll
          for (int t = 0; t < LM2; ++t){
            if (t < nlay){
              const float4* A0 = (c0[t] == RC) ? cv4 : (const float4*)&tl[c0[t] * SROW];
              const float4* A1 = (c1[t] == RC) ? cv4 : (const float4*)&tl[c1[t] * SROW];
              const float4* Bp0 = (c2[t] == RC) ? cv4 : (const float4*)&tl[c2[t] * SROW];
              const float4* Bp1 = (c3[t] == RC) ? cv4 : (const float4*)&tl[c3[t] * SROW];
              float s00 = 0.f, s01 = 0.f, s10 = 0.f, s11 = 0.f;
#pragma unroll 8
              for (int j = 0; j < CK/4; ++j){
                float4 a0 = A0[j], a1 = A1[j], b0 = Bp0[j], b1 = Bp1[j];
                s00 += dot4(a0, b0); s01 += dot4(a0, b1);
                s10 += dot4(a1, b0); s11 += dot4(a1, b1);
              }
              acc[t][0] += s00; acc[t][1] += s01;
              acc[t][2] += s10; acc[t][3] += s11;
            }
          }
        }
        if (ch + 1 < NCH){
          float* tn = tile + (cur ^ 1) * TILE_F;
#pragma unroll
          for (int k = 0; k < SPT; ++k){
            int e = tid + k * NT;
            if (e < nst){
              int r = e >> 5, j = e & 31;
              ((float4*)&tn[r * SROW])[j] = pf[k];
            }
          }
          if (tid < CK/4) ((float4*)cvec[cur ^ 1])[tid] = cpf;
        }
        __syncthreads();
      }
#pragma unroll
      for (int t = 0; t < LM2; ++t)
        asm volatile("" :: "v"(acc[t][0]), "v"(acc[t][1]), "v"(acc[t][2]), "v"(acc[t][3]));
      __syncthreads();
    }
  }
}

// ==== DIAG 2: phase A + 3x {synthetic fill -> C normalize/minmax -> D
// two-level ballot select -> exact recount -> E loss}. No global writes.
// Hash-distinct pd values -> realistic rank-select. Duration ~= A + 3*Sel. ====
__global__ __launch_bounds__(NT) void k_diag_sel(const int* __restrict__ labels)
{
  const int c = blockIdx.x;
  const int tid = threadIdx.x;
  const int wid = tid >> 6, lane = tid & 63;

  __shared__ int   gid_s[M_MAX];
  __shared__ int   mcount;
  __shared__ __align__(16) float tile[2 * TILE_F];   // match k_all LDS footprint
  float*          Sl     = tile;
  float*          Pd     = tile + P_MAX;
  unsigned short* fidx_s = (unsigned short*)(tile + 2 * P_MAX);
  __shared__ float selfs[M_MAX];
  __shared__ float ecs[M_MAX];
  __shared__ int   wcnt[NW * 64];
  __shared__ float mnb[NW], mxb[NW];
  __shared__ float lo_sh, sF_sh;
  __shared__ int   B0_sh, ex_sh, B1_sh;
  __shared__ float thr_sh;

  if (tid == 0) mcount = 0;
  __syncthreads();
  {
    const int4* lab4 = (const int4*)labels;
    for (int i = tid; i < B_ / 4; i += NT){
      int4 L = lab4[i];
      int base = i << 2;
      if (L.x == c){ int p = atomicAdd(&mcount, 1); if (p < M_MAX) gid_s[p] = base; }
      if (L.y == c){ int p = atomicAdd(&mcount, 1); if (p < M_MAX) gid_s[p] = base + 1; }
      if (L.z == c){ int p = atomicAdd(&mcount, 1); if (p < M_MAX) gid_s[p] = base + 2; }
      if (L.w == c){ int p = atomicAdd(&mcount, 1); if (p < M_MAX) gid_s[p] = base + 3; }
    }
  }
  __syncthreads();
  const int m = mcount;

  float lloss = 0.f, lw = 0.f;

  if (m >= 2 && m <= M_MAX){
    const int P = m * (m - 1) / 2;
    const int k0 = (P - 1) >> 1;
    const float wc = (float)m;

    for (int rep = 0; rep < 3; ++rep){
      // synthetic raw-dot fill: distinct, well-spread values in (0,1)
      for (int p = tid; p < P; p += NT){
        unsigned hsh = ((unsigned)p * 2654435761u) ^ ((unsigned)(rep + 1) * 0x9E3779B9u);
        hsh ^= hsh >> 16; hsh *= 0x85EBCA6Bu;
        float pdh = (float)(hsh >> 9) * (1.f / 8388608.f);
        Sl[p] = 1.f - pdh;
      }
      if (tid < m){ selfs[tid] = 1.f; ecs[tid] = 0.5f; }
      __syncthreads();

      // phase C
      float pmn = 1e30f, pmx = -1e30f;
      for (int p = tid; p < P; p += NT){
        int a, b; decode_pair(p, m, &a, &b);
        float S = Sl[p] * selfs[a] * selfs[b];
        float pd = 1.f - clamp1(S);
        Sl[p] = S; Pd[p] = pd;
        pmn = fminf(pmn, pd); pmx = fmaxf(pmx, pd);
      }
      pmn = wave_min(pmn); pmx = wave_max(pmx);
      if (lane == 0){ mnb[wid] = pmn; mxb[wid] = pmx; }
      __syncthreads();
      if (tid == 0){
        float mn = mnb[0], mx = mxb[0];
#pragma unroll
        for (int i = 1; i < NW; ++i){ mn = fminf(mn, mnb[i]); mx = fmaxf(mx, mxb[i]); }
        lo_sh = mn;
        sF_sh = 4096.f / fmaxf(mx - mn, 1e-20f);
      }
      __syncthreads();
      const float lo = lo_sh, sF = sF_sh;

      // phase D
      const int nch = (P + NT - 1) / NT;
      int cl = 0;
      for (int t = 0; t < nch; ++t){
        int p = tid + t * NT;
        int bkt = -1;
        if (p < P){
          int f = (int)((Pd[p] - lo) * sF);
          f = max(0, min(4095, f));
          fidx_s[p] = (unsigned short)f;
          bkt = f >> 6;
        }
#pragma unroll
        for (int k = 0; k < 64; ++k){
          unsigned long long msk = __ballot(bkt == k);
          if (lane == k) cl += __popcll(msk);
        }
      }
      wcnt[wid*64 + lane] = cl;
      __syncthreads();
      if (tid < 64){
        int tot = 0;
#pragma unroll
        for (int w = 0; w < NW; ++w) tot += wcnt[w*64 + tid];
        int inc = tot;
#pragma unroll
        for (int o = 1; o < 64; o <<= 1){
          int v = __shfl_up(inc, o, 64);
          if (tid >= o) inc += v;
        }
        int excl = inc - tot;
        if (excl <= k0 && k0 < inc){ B0_sh = tid; ex_sh = excl; }
      }
      __syncthreads();
      const int Bsel0 = B0_sh;
      const int kt = k0 - ex_sh;
      cl = 0;
      for (int t = 0; t < nch; ++t){
        int p = tid + t * NT;
        int bkt = -1;
        if (p < P){
          int f = fidx_s[p];
          if ((f >> 6) == Bsel0) bkt = f & 63;
        }
#pragma unroll
        for (int k = 0; k < 64; ++k){
          unsigned long long msk = __ballot(bkt == k);
          if (lane == k) cl += __popcll(msk);
        }
      }
      wcnt[wid*64 + lane] = cl;
      __syncthreads();
      if (tid < 64){
        int tot = 0;
#pragma unroll
        for (int w = 0; w < NW; ++w) tot += wcnt[w*64 + tid];
        int inc = tot;
#pragma unroll
        for (int o = 1; o < 64; o <<= 1){
          int v = __shfl_up(inc, o, 64);
          if (tid >= o) inc += v;
        }
        int excl = inc - tot;
        if (excl <= kt && kt < inc) B1_sh = tid;
      }
      __syncthreads();
      const int fsel = (Bsel0 << 6) | B1_sh;

      // exact recount
      {
        const float4* Pd4 = (const float4*)Pd;
        const int nq4 = P >> 2;
        for (int p = tid; p < P; p += NT){
          if (fidx_s[p] == (unsigned short)fsel){
            const float pdp = Pd[p];
            int lt = 0, eq = 0;
#pragma unroll 4
            for (int q4 = 0; q4 < nq4; ++q4){
              float4 v = Pd4[q4];
              lt += (v.x < pdp) + (v.y < pdp) + (v.z < pdp) + (v.w < pdp);
              eq += (v.x == pdp) + (v.y == pdp) + (v.z == pdp) + (v.w == pdp);
            }
            for (int q = nq4 << 2; q < P; ++q){
              float pdq = Pd[q];
              lt += (pdq < pdp); eq += (pdq == pdp);
            }
            if (lt <= k0 && k0 < lt + eq) thr_sh = pdp;
          }
        }
      }
      __syncthreads();
      const float thr = thr_sh;

      // phase E
      for (int p = tid; p < P; p += NT){
        float pd = Pd[p];
        if (pd > thr){
          float S = Sl[p];
          int a, b; decode_pair(p, m, &a, &b);
          int ga = gid_s[a], gb = gid_s[b];
          float ea = ecs[a], eb = ecs[b];
          int i, j; float eci, ecj;
          if (ga < gb){ i = ga; j = gb; eci = ea; ecj = eb; }
          else        { i = gb; j = ga; eci = eb; ecj = ea; }
          float r = rand_ij((unsigned)i * (unsigned)B_ + (unsigned)j);
          float omr = 1.f - r;
          float n2 = r * r + omr * omr + 2.f * r * omr * S;
          float nrm = fmaxf(sqrtf(fmaxf(n2, 0.f)), 1e-12f);
          float dt = clamp1((r * eci + omr * ecj) / nrm);
          lloss += wc * (1.f - dt);
          lw += wc;
        }
      }
      __syncthreads();
    }
  }
  asm volatile("" :: "v"(lloss), "v"(lw));
}

// ==== DIAG 3: 8x phase A label scan. Duration ~= 8*A. No global writes. ====
__global__ __launch_bounds__(NT) void k_diag_a(const int* __restrict__ labels)
{
  const int c = blockIdx.x;
  const int tid = threadIdx.x;
  __shared__ int gid_s[M_MAX];
  __shared__ int mcount;

  int msum = 0;
  for (int rep = 0; rep < 8; ++rep){
    if (tid == 0) mcount = 0;
    __syncthreads();
    int zo = 0;
    asm volatile("" : "+v"(zo));
    const int4* lab4 = (const int4*)labels;
    for (int i = tid; i < B_ / 4; i += NT){
      int4 L = lab4[i + zo];
      int base = i << 2;
      if (L.x == c){ int p = atomicAdd(&mcount, 1); if (p < M_MAX) gid_s[p] = base; }
      if (L.y == c){ int p = atomicAdd(&mcount, 1); if (p < M_MAX) gid_s[p] = base + 1; }
      if (L.z == c){ int p = atomicAdd(&mcount, 1); if (p < M_MAX) gid_s[p] = base + 2; }
      if (L.w == c){ int p = atomicAdd(&mcount, 1); if (p < M_MAX) gid_s[p] = base + 3; }
    }
    __syncthreads();
    msum += mcount;
    __syncthreads();
  }
  asm volatile("" :: "v"(msum));
  if (tid == 0) asm volatile("" :: "v"(gid_s[0]));
}

extern "C" void kernel_launch(void* const* d_in, const int* in_sizes, int n_in,
                              void* d_out, int out_size, void* d_ws, size_t ws_size,
                              hipStream_t stream)
{
  const float* feat   = (const float*)d_in[0];
  const float* cent   = (const float*)d_in[1];
  const int*   labels = (const int*)d_in[2];
  // d_in[3] = cam_ids: unused by the reference computation.

  char* ws = (char*)d_ws;
  float*    lossv = (float*)(ws + 0);      // 128 floats
  float*    wvv   = (float*)(ws + 512);    // 128 floats
  unsigned* flags = (unsigned*)(ws + 1024);// [0] = arrival counter (mod-128 trigger)

  // main kernel first (unchanged R6; writes out). Diagnostics after: no
  // global writes, pure timing probes for the rocprof dispatch table.
  k_all<<<C_, NT, 0, stream>>>(feat, cent, labels, lossv, wvv, flags, (float*)d_out);
  k_diag_gram<<<C_, NT, 0, stream>>>(feat, cent, labels);
  k_diag_sel<<<C_, NT, 0, stream>>>(labels);
  k_diag_a<<<C_, NT, 0, stream>>>(labels);
}

// Round 8
// 153.578 us; speedup vs baseline: 1.8843x; 1.8843x over previous
//
#include <hip/hip_runtime.h>

#define B_ 4096
#define C_ 128
#define D_ 768
#define NT 1024
#define NW (NT/64)                  // 16 waves
#define M_MAX 96
#define P_MAX (M_MAX*(M_MAX-1)/2)   // 4560
#define CK 128
#define NCH (D_/CK)                 // 6
#define SROW 132                    // floats; bank(row r) = 4r mod 32 -> consecutive rows spread 8 banks
#define TILE_F (M_MAX*SROW)         // 12672 floats per buffer
#define LM2 2                       // max 2x2 units per thread: U <= 1225 < 2*NT
#define RC 127                      // row code meaning "cvec"
#define SPT ((M_MAX*(CK/4) + NT - 1)/NT)    // 3 staging float4s per thread

__device__ __forceinline__ float wave_red(float v){
#pragma unroll
  for (int o = 32; o > 0; o >>= 1) v += __shfl_down(v, o, 64);
  return v;
}
__device__ __forceinline__ float clamp1(float x){ return fminf(fmaxf(x, -1.f), 1.f); }
__device__ __forceinline__ unsigned rotl32(unsigned x, int r){ return (x << r) | (x >> (32 - r)); }
__device__ __forceinline__ float dot4(float4 a, float4 b){
  return fmaf(a.x, b.x, fmaf(a.y, b.y, fmaf(a.z, b.z, a.w * b.w)));
}

// jax.random.uniform(jax.random.key(1),(B,B)) element n: Threefry-2x32 key (0,1),
// counters split in halves. Bit-exact (verified: absmax 0.0 across all rounds).
__device__ float rand_ij(unsigned n){
  const unsigned half = (unsigned)B_ * (unsigned)B_ / 2u;
  unsigned c0, c1; bool hi;
  if (n < half){ c0 = n; c1 = n + half; hi = false; }
  else         { c0 = n - half; c1 = n; hi = true; }
  const unsigned K0 = 0u, K1 = 1u, K2 = 0x1BD11BDBu;
  unsigned x0 = c0 + K0, x1 = c1 + K1;
#define TFR(r) { x0 += x1; x1 = rotl32(x1, (r)); x1 ^= x0; }
  TFR(13) TFR(15) TFR(26) TFR(6)  x0 += K1; x1 += K2 + 1u;
  TFR(17) TFR(29) TFR(16) TFR(24) x0 += K2; x1 += K0 + 2u;
  TFR(13) TFR(15) TFR(26) TFR(6)  x0 += K0; x1 += K1 + 3u;
  TFR(17) TFR(29) TFR(16) TFR(24) x0 += K1; x1 += K2 + 4u;
  TFR(13) TFR(15) TFR(26) TFR(6)  x0 += K2; x1 += K0 + 5u;
#undef TFR
  unsigned bits = hi ? x1 : x0;
  return __uint_as_float((bits >> 9) | 0x3F800000u) - 1.0f;
}

// p -> (a,b), a<b<m, row-major upper-tri. before(a) = a*(2m-1-a)/2.
__device__ __forceinline__ void decode_pair(int p, int m, int* a_, int* b_){
  float fm = (float)(2*m - 1);
  int a = (int)((fm - sqrtf(fm*fm - 8.0f*(float)p)) * 0.5f);
  a = max(0, min(a, m - 2));
  while (a > 0 && (a*(2*m - 1 - a))/2 > p) --a;
  while (((a + 1)*(2*m - 2 - a))/2 <= p) ++a;
  *a_ = a;
  *b_ = a + 1 + (p - (a*(2*m - 1 - a))/2);
}

// ---- slow-path helpers (unreachable: all classes m<=96; insurance only) ----
__device__ float dotg(const float* x, const float* y){
  float s = 0.f;
  for (int k = 0; k < D_; ++k) s = fmaf(x[k], y[k], s);
  return s;
}
__device__ float S_pair_g(const float* feat, int ga, int gb){
  const float* ra = feat + (size_t)ga * D_;
  const float* rb = feat + (size_t)gb * D_;
  float d = dotg(ra, rb);
  float na = 1.f / fmaxf(sqrtf(dotg(ra, ra)), 1e-12f);
  float nb = 1.f / fmaxf(sqrtf(dotg(rb, rb)), 1e-12f);
  return d * na * nb;
}

// ==== single kernel: R6 gram (split-row 2x2) + NEW histogram rank-select.
// pd in [0,2] exactly -> fixed monotone quant f = min(4095, pd*2048);
// 4096-bin + 64-bin LDS-atomic histograms replace the 256-step ballot
// machinery; thr still from the exact float-compare recount (bit-exact).
// Last-arriver completion (R5). ====
__global__ __launch_bounds__(NT) void k_all(
    const float* __restrict__ feat, const float* __restrict__ cent,
    const int* __restrict__ labels,
    float* __restrict__ lossv, float* __restrict__ wv,
    unsigned* __restrict__ flags, float* __restrict__ out)
{
  const int c = blockIdx.x;
  const int tid = threadIdx.x;
  const int wid = tid >> 6, lane = tid & 63;

  __shared__ int   gid_s[M_MAX];
  __shared__ int   mcount;
  __shared__ __align__(16) float tile[2 * TILE_F];     // 101376 B, double-buffered
  __shared__ __align__(16) float cvec[2][CK];
  // select arrays overlay tile buffer 0 (used only after the last gram, which
  // reads buffer 1): Sl(P) + Pd(P) + fidx(P/2) = 11400 floats <= 12672.
  // hist overlays buffer 1 (free after the gram loop ends): 4096 ints.
  float*          Sl     = tile;
  float*          Pd     = tile + P_MAX;
  unsigned short* fidx_s = (unsigned short*)(tile + 2 * P_MAX);
  int*            hist   = (int*)(tile + TILE_F);
  __shared__ float selfs[M_MAX];
  __shared__ float ecs[M_MAX];
  __shared__ float cn_sh;
  __shared__ int   coarse[64];
  __shared__ int   B0_sh, ex_sh, B1_sh;
  __shared__ float thr_sh;
  __shared__ float redbuf[2 * NW];
  __shared__ int   last_sh;

  // ---- phase A: collect members of class c (int4 label loads) ----
  if (tid == 0) mcount = 0;
  __syncthreads();
  {
    const int4* lab4 = (const int4*)labels;
    for (int i = tid; i < B_ / 4; i += NT){
      int4 L = lab4[i];
      int base = i << 2;
      if (L.x == c){ int p = atomicAdd(&mcount, 1); if (p < M_MAX) gid_s[p] = base; }
      if (L.y == c){ int p = atomicAdd(&mcount, 1); if (p < M_MAX) gid_s[p] = base + 1; }
      if (L.z == c){ int p = atomicAdd(&mcount, 1); if (p < M_MAX) gid_s[p] = base + 2; }
      if (L.w == c){ int p = atomicAdd(&mcount, 1); if (p < M_MAX) gid_s[p] = base + 3; }
    }
  }
  __syncthreads();
  const int m = mcount;

  float lloss = 0.f, lw = 0.f;

  if (m >= 2 && m <= M_MAX){
    const int P = m * (m - 1) / 2;
    const int k0 = (P - 1) >> 1;
    const float wc = (float)m;
    const int nst = m * (CK / 4);

    // ---- unit setup: split-row 2x2 tiles + split-row ec units (R6) ----
    const int h    = (m + 1) >> 1;
    const int Upair = h * (h + 1) / 2;
    const int hec  = (m + 2) >> 1;
    const int U    = Upair + hec;

    int c0[LM2], c1[LM2], c2[LM2], c3[LM2];
    int tAv[LM2], tBv[LM2];
    float acc[LM2][4];
    int nlay = 0;
#pragma unroll
    for (int t = 0; t < LM2; ++t){
      acc[t][0] = acc[t][1] = acc[t][2] = acc[t][3] = 0.f;
      c0[t] = c1[t] = c2[t] = c3[t] = 0; tAv[t] = 0; tBv[t] = -3;
      int u = tid + t * NT;
      if (u < U){
        nlay = t + 1;
        if (u < Upair){
          int ta = 0;
          while ((ta + 1) * h - ((ta + 1) * ta) / 2 <= u) ++ta;
          int tb = ta + (u - (ta * h - (ta * (ta - 1)) / 2));
          c0[t] = ta; c1[t] = ta + h; c2[t] = tb; c3[t] = tb + h;
          tAv[t] = ta; tBv[t] = tb;
        } else {
          int g = u - Upair;
          int l1 = g + hec;
          c0[t] = g;
          c1[t] = (l1 == m) ? RC : ((l1 < m) ? l1 : 0);
          c2[t] = RC; c3[t] = RC;
          tAv[t] = g; tBv[t] = -1;
        }
      }
    }

    // ---- phase B: double-buffered staging; single barrier per chunk ----
    float4 pf[SPT];
    float4 cpf;
#pragma unroll
    for (int k = 0; k < SPT; ++k){
      int e = tid + k * NT;
      if (e < nst){
        int r = e >> 5, j = e & 31;
        pf[k] = ((const float4*)(feat + (size_t)gid_s[r] * D_))[j];
      }
    }
    if (tid < CK/4) cpf = ((const float4*)(cent + (size_t)c * D_))[tid];
#pragma unroll
    for (int k = 0; k < SPT; ++k){
      int e = tid + k * NT;
      if (e < nst){
        int r = e >> 5, j = e & 31;
        ((float4*)&tile[r * SROW])[j] = pf[k];
      }
    }
    if (tid < CK/4) ((float4*)cvec[0])[tid] = cpf;
    __syncthreads();

    for (int ch = 0; ch < NCH; ++ch){
      const int cur = ch & 1;
      if (ch + 1 < NCH){
        const int d0 = (ch + 1) * CK;
#pragma unroll
        for (int k = 0; k < SPT; ++k){
          int e = tid + k * NT;
          if (e < nst){
            int r = e >> 5, j = e & 31;
            pf[k] = ((const float4*)(feat + (size_t)gid_s[r] * D_ + d0))[j];
          }
        }
        if (tid < CK/4) cpf = ((const float4*)(cent + (size_t)c * D_ + d0))[tid];
      }
      {
        const float* tl = tile + cur * TILE_F;
        const float4* cv4 = (const float4*)cvec[cur];
#pragma unroll
        for (int t = 0; t < LM2; ++t){
          if (t < nlay){
            const float4* A0 = (c0[t] == RC) ? cv4 : (const float4*)&tl[c0[t] * SROW];
            const float4* A1 = (c1[t] == RC) ? cv4 : (const float4*)&tl[c1[t] * SROW];
            const float4* Bp0 = (c2[t] == RC) ? cv4 : (const float4*)&tl[c2[t] * SROW];
            const float4* Bp1 = (c3[t] == RC) ? cv4 : (const float4*)&tl[c3[t] * SROW];
            float s00 = 0.f, s01 = 0.f, s10 = 0.f, s11 = 0.f;
#pragma unroll 8
            for (int j = 0; j < CK/4; ++j){
              float4 a0 = A0[j], a1 = A1[j], b0 = Bp0[j], b1 = Bp1[j];
              s00 += dot4(a0, b0); s01 += dot4(a0, b1);
              s10 += dot4(a1, b0); s11 += dot4(a1, b1);
            }
            acc[t][0] += s00; acc[t][1] += s01;
            acc[t][2] += s10; acc[t][3] += s11;
          }
        }
      }
      if (ch + 1 < NCH){
        float* tn = tile + (cur ^ 1) * TILE_F;
#pragma unroll
        for (int k = 0; k < SPT; ++k){
          int e = tid + k * NT;
          if (e < nst){
            int r = e >> 5, j = e & 31;
            ((float4*)&tn[r * SROW])[j] = pf[k];
          }
        }
        if (tid < CK/4) ((float4*)cvec[cur ^ 1])[tid] = cpf;
      }
      __syncthreads();
    }

    // combine: owner-writes raw dots (buffer-0 overlay; last gram read buf 1)
#pragma unroll
    for (int t = 0; t < LM2; ++t){
      if (t < nlay){
        if (tBv[t] == -1){
          int g = tAv[t], l1 = g + hec;
          ecs[g] = acc[t][0];
          if (l1 == m) cn_sh = acc[t][2];
          else if (l1 < m) ecs[l1] = acc[t][2];
        } else if (tBv[t] >= 0){
          const int ta = tAv[t], tb = tBv[t];
          const int a1 = ta + h, b1 = tb + h;
          if (ta == tb){
            if (ta < m) selfs[ta] = acc[t][0];
            if (a1 < m) selfs[a1] = acc[t][3];
            if (b1 < m) Sl[(ta*(2*m - 1 - ta))/2 + (b1 - ta - 1)] = acc[t][1];
          } else {
            Sl[(ta*(2*m - 1 - ta))/2 + (tb - ta - 1)] = acc[t][0];
            if (b1 < m) Sl[(ta*(2*m - 1 - ta))/2 + (b1 - ta - 1)] = acc[t][1];
            if (a1 < m) Sl[(tb*(2*m - 1 - tb))/2 + (a1 - tb - 1)] = acc[t][2];
            if (a1 < m && b1 < m) Sl[(a1*(2*m - 1 - a1))/2 + (b1 - a1 - 1)] = acc[t][3];
          }
        }
      }
    }
    __syncthreads();
    // normalize selfs/ecs; zero histograms (buffer 1 is free now) in parallel
    for (int i = tid; i < 4096; i += NT) hist[i] = 0;
    if (tid < 64) coarse[tid] = 0;
    if (tid < m){
      float rn  = 1.f / fmaxf(sqrtf(selfs[tid]), 1e-12f);
      float cno = 1.f / fmaxf(sqrtf(cn_sh), 1e-12f);
      selfs[tid] = rn;
      ecs[tid] = ecs[tid] * rn * cno;
    }
    __syncthreads();

    // ---- phase C+D-fill fused: normalize pairs, fixed [0,2] quantization,
    // LDS-atomic histogram (fine 4096 + coarse 64) ----
    for (int p = tid; p < P; p += NT){
      int a, b; decode_pair(p, m, &a, &b);
      float S = Sl[p] * selfs[a] * selfs[b];
      float pd = 1.f - clamp1(S);          // in [0,2] exactly
      Sl[p] = S; Pd[p] = pd;
      int f = min(4095, (int)(pd * 2048.f));
      fidx_s[p] = (unsigned short)f;
      atomicAdd(&hist[f], 1);
      atomicAdd(&coarse[f >> 6], 1);
    }
    __syncthreads();

    // ---- rank-select: two conflict-free single-wave prefix scans ----
    if (tid < 64){
      int cnt = coarse[tid];
      int inc = cnt;
#pragma unroll
      for (int o = 1; o < 64; o <<= 1){
        int v = __shfl_up(inc, o, 64);
        if (tid >= o) inc += v;
      }
      int excl = inc - cnt;
      if (excl <= k0 && k0 < inc){ B0_sh = tid; ex_sh = excl; }
    }
    __syncthreads();
    const int Bsel0 = B0_sh;
    const int kt = k0 - ex_sh;
    if (tid < 64){
      int cnt = hist[(Bsel0 << 6) + tid];
      int inc = cnt;
#pragma unroll
      for (int o = 1; o < 64; o <<= 1){
        int v = __shfl_up(inc, o, 64);
        if (tid >= o) inc += v;
      }
      int excl = inc - cnt;
      if (excl <= kt && kt < inc) B1_sh = tid;
    }
    __syncthreads();
    const int fsel = (Bsel0 << 6) | B1_sh;

    // exact recount for the ~1-2 candidates in the fine bucket (bit-exact thr)
    {
      const float4* Pd4 = (const float4*)Pd;
      const int nq4 = P >> 2;
      for (int p = tid; p < P; p += NT){
        if (fidx_s[p] == (unsigned short)fsel){
          const float pdp = Pd[p];
          int lt = 0, eq = 0;
#pragma unroll 4
          for (int q4 = 0; q4 < nq4; ++q4){
            float4 v = Pd4[q4];
            lt += (v.x < pdp) + (v.y < pdp) + (v.z < pdp) + (v.w < pdp);
            eq += (v.x == pdp) + (v.y == pdp) + (v.z == pdp) + (v.w == pdp);
          }
          for (int q = nq4 << 2; q < P; ++q){
            float pdq = Pd[q];
            lt += (pdq < pdp); eq += (pdq == pdp);
          }
          if (lt <= k0 && k0 < lt + eq) thr_sh = pdp;
        }
      }
    }
    __syncthreads();
    const float thr = thr_sh;

    // ---- phase E: loss over selected pairs ----
    for (int p = tid; p < P; p += NT){
      float pd = Pd[p];
      if (pd > thr){
        float S = Sl[p];
        int a, b; decode_pair(p, m, &a, &b);
        int ga = gid_s[a], gb = gid_s[b];
        float ea = ecs[a], eb = ecs[b];
        int i, j; float eci, ecj;
        if (ga < gb){ i = ga; j = gb; eci = ea; ecj = eb; }
        else        { i = gb; j = ga; eci = eb; ecj = ea; }
        float r = rand_ij((unsigned)i * (unsigned)B_ + (unsigned)j);
        float omr = 1.f - r;
        float n2 = r * r + omr * omr + 2.f * r * omr * S;    // raw (unclipped) S
        float nrm = fmaxf(sqrtf(fmaxf(n2, 0.f)), 1e-12f);
        float dt = clamp1((r * eci + omr * ecj) / nrm);
        lloss += wc * (1.f - dt);
        lw += wc;
      }
    }
  } else if (m > M_MAX){
    // correctness-only fallback (impossible here: all m<=96, verified)
    int* mem = (int*)Sl;
    if (tid == 0) B0_sh = 0;
    __syncthreads();
    for (int i = tid; i < B_; i += NT)
      if (labels[i] == c){ int p = atomicAdd(&B0_sh, 1); mem[p] = i; }
    __syncthreads();
    const int P = m * (m - 1) / 2;
    const int k0 = (P - 1) >> 1;
    const float wc = (float)m;
    const float* cc = cent + (size_t)c * D_;
    const float cno = 1.f / fmaxf(sqrtf(dotg(cc, cc)), 1e-12f);
    for (int p = tid; p < P; p += NT){
      int a, b; decode_pair(p, m, &a, &b);
      float pdp = 1.f - clamp1(S_pair_g(feat, mem[a], mem[b]));
      int lt = 0, eq = 0;
      for (int q = 0; q < P; ++q){
        int a2, b2; decode_pair(q, m, &a2, &b2);
        float pdq = 1.f - clamp1(S_pair_g(feat, mem[a2], mem[b2]));
        lt += (pdq < pdp); eq += (pdq == pdp);
      }
      if (lt <= k0 && k0 < lt + eq) thr_sh = pdp;
    }
    __syncthreads();
    const float thr = thr_sh;
    for (int p = tid; p < P; p += NT){
      int a, b; decode_pair(p, m, &a, &b);
      int ga = mem[a], gb = mem[b];
      float S = S_pair_g(feat, ga, gb);
      float pd = 1.f - clamp1(S);
      if (pd > thr){
        if (ga > gb){ int t2 = ga; ga = gb; gb = t2; }
        const float* ra = feat + (size_t)ga * D_;
        const float* rb = feat + (size_t)gb * D_;
        float eci = dotg(ra, cc) / fmaxf(sqrtf(dotg(ra, ra)), 1e-12f) * cno;
        float ecj = dotg(rb, cc) / fmaxf(sqrtf(dotg(rb, rb)), 1e-12f) * cno;
        float r = rand_ij((unsigned)ga * (unsigned)B_ + (unsigned)gb);
        float omr = 1.f - r;
        float n2 = r * r + omr * omr + 2.f * r * omr * S;
        float nrm = fmaxf(sqrtf(fmaxf(n2, 0.f)), 1e-12f);
        float dt = clamp1((r * eci + omr * ecj) / nrm);
        lloss += wc * (1.f - dt);
        lw += wc;
      }
    }
  }
  // m < 2: contributes zeros

  // ---- phase F: last-arriver completion (R5). Publish partials (relaxed),
  // one acq_rel counter RMW, exit; the 128th arriver reduces. Init-agnostic:
  // any 128 consecutive olds contain exactly one ==127 (mod 128); stale
  // partial values are replay-invariant, so cross-launch reads are benign.
  lloss = wave_red(lloss); lw = wave_red(lw);
  if (lane == 0){ redbuf[wid] = lloss; redbuf[NW + wid] = lw; }
  __syncthreads();
  if (tid == 0){
    float tl = 0.f, tw = 0.f;
#pragma unroll
    for (int i = 0; i < NW; ++i){ tl += redbuf[i]; tw += redbuf[NW + i]; }
    __hip_atomic_store(&lossv[c], tl, __ATOMIC_RELAXED, __HIP_MEMORY_SCOPE_AGENT);
    __hip_atomic_store(&wv[c],   tw, __ATOMIC_RELAXED, __HIP_MEMORY_SCOPE_AGENT);
    unsigned old = __hip_atomic_fetch_add(&flags[0], 1u, __ATOMIC_ACQ_REL,
                                          __HIP_MEMORY_SCOPE_AGENT);
    last_sh = ((old & 127u) == 127u) ? 1 : 0;
  }
  __syncthreads();
  if (last_sh){
    float lv = 0.f, wvv = 0.f;
    if (tid < C_){
      lv  = __hip_atomic_load(&lossv[tid], __ATOMIC_RELAXED, __HIP_MEMORY_SCOPE_AGENT);
      wvv = __hip_atomic_load(&wv[tid],   __ATOMIC_RELAXED, __HIP_MEMORY_SCOPE_AGENT);
    }
    lv = wave_red(lv); wvv = wave_red(wvv);
    if (lane == 0){ redbuf[wid] = lv; redbuf[NW + wid] = wvv; }
    __syncthreads();
    if (tid == 0){
      float l = redbuf[0] + redbuf[1];
      float w = redbuf[NW] + redbuf[NW + 1];
      out[0] = (w > 0.f) ? (l / w) : 0.f;
    }
  }
}

extern "C" void kernel_launch(void* const* d_in, const int* in_sizes, int n_in,
                              void* d_out, int out_size, void* d_ws, size_t ws_size,
                              hipStream_t stream)
{
  const float* feat   = (const float*)d_in[0];
  const float* cent   = (const float*)d_in[1];
  const int*   labels = (const int*)d_in[2];
  // d_in[3] = cam_ids: unused by the reference computation.

  char* ws = (char*)d_ws;
  float*    lossv = (float*)(ws + 0);      // 128 floats
  float*    wvv   = (float*)(ws + 512);    // 128 floats
  unsigned* flags = (unsigned*)(ws + 1024);// [0] = arrival counter (mod-128 trigger)

  // single graph node: no memset needed (kernel is init-agnostic on ws)
  k_all<<<C_, NT, 0, stream>>>(feat, cent, labels, lossv, wvv, flags, (float*)d_out);
}

// Round 9
// 112.856 us; speedup vs baseline: 2.5641x; 1.3608x over previous
//
#include <hip/hip_runtime.h>

#define B_ 4096
#define C_ 128
#define D_ 768
#define NT 1024
#define NW (NT/64)                  // 16 waves
#define M_MAX 96
#define P_MAX (M_MAX*(M_MAX-1)/2)   // 4560
#define CK 128
#define NCH (D_/CK)                 // 6
#define SROW 132                    // floats; bank(row r) = 4r mod 32 -> consecutive rows spread 8 banks
#define TILE_F (M_MAX*SROW)         // 12672 floats per buffer
#define LM2 2                       // max 2x2 units per thread: U <= 1225 < 2*NT
#define RC 127                      // row code meaning "cvec"
#define SPT ((M_MAX*(CK/4) + NT - 1)/NT)    // 3 staging float4s per thread
#define LCAP 64                     // in-bin candidate list cap (expected ~7)

__device__ __forceinline__ float wave_red(float v){
#pragma unroll
  for (int o = 32; o > 0; o >>= 1) v += __shfl_down(v, o, 64);
  return v;
}
__device__ __forceinline__ float clamp1(float x){ return fminf(fmaxf(x, -1.f), 1.f); }
__device__ __forceinline__ unsigned rotl32(unsigned x, int r){ return (x << r) | (x >> (32 - r)); }
__device__ __forceinline__ float dot4(float4 a, float4 b){
  return fmaf(a.x, b.x, fmaf(a.y, b.y, fmaf(a.z, b.z, a.w * b.w)));
}

// jax.random.uniform(jax.random.key(1),(B,B)) element n: Threefry-2x32 key (0,1),
// counters split in halves. Bit-exact (verified: absmax 0.0 across all rounds).
__device__ float rand_ij(unsigned n){
  const unsigned half = (unsigned)B_ * (unsigned)B_ / 2u;
  unsigned c0, c1; bool hi;
  if (n < half){ c0 = n; c1 = n + half; hi = false; }
  else         { c0 = n - half; c1 = n; hi = true; }
  const unsigned K0 = 0u, K1 = 1u, K2 = 0x1BD11BDBu;
  unsigned x0 = c0 + K0, x1 = c1 + K1;
#define TFR(r) { x0 += x1; x1 = rotl32(x1, (r)); x1 ^= x0; }
  TFR(13) TFR(15) TFR(26) TFR(6)  x0 += K1; x1 += K2 + 1u;
  TFR(17) TFR(29) TFR(16) TFR(24) x0 += K2; x1 += K0 + 2u;
  TFR(13) TFR(15) TFR(26) TFR(6)  x0 += K0; x1 += K1 + 3u;
  TFR(17) TFR(29) TFR(16) TFR(24) x0 += K1; x1 += K2 + 4u;
  TFR(13) TFR(15) TFR(26) TFR(6)  x0 += K2; x1 += K0 + 5u;
#undef TFR
  unsigned bits = hi ? x1 : x0;
  return __uint_as_float((bits >> 9) | 0x3F800000u) - 1.0f;
}

// p -> (a,b), a<b<m, row-major upper-tri. before(a) = a*(2m-1-a)/2.
__device__ __forceinline__ void decode_pair(int p, int m, int* a_, int* b_){
  float fm = (float)(2*m - 1);
  int a = (int)((fm - sqrtf(fm*fm - 8.0f*(float)p)) * 0.5f);
  a = max(0, min(a, m - 2));
  while (a > 0 && (a*(2*m - 1 - a))/2 > p) --a;
  while (((a + 1)*(2*m - 2 - a))/2 <= p) ++a;
  *a_ = a;
  *b_ = a + 1 + (p - (a*(2*m - 1 - a))/2);
}

// ---- slow-path helpers (unreachable: all classes m<=96; insurance only) ----
__device__ float dotg(const float* x, const float* y){
  float s = 0.f;
  for (int k = 0; k < D_; ++k) s = fmaf(x[k], y[k], s);
  return s;
}
__device__ float S_pair_g(const float* feat, int ga, int gb){
  const float* ra = feat + (size_t)ga * D_;
  const float* rb = feat + (size_t)gb * D_;
  float d = dotg(ra, rb);
  float na = 1.f / fmaxf(sqrtf(dotg(ra, ra)), 1e-12f);
  float nb = 1.f / fmaxf(sqrtf(dotg(rb, rb)), 1e-12f);
  return d * na * nb;
}

// ==== single kernel: R6 gram (split-row 2x2) + REGISTERIZED pair pipeline:
// S/pd/f computed straight from acc registers (no decode_pair, no raw-dot
// LDS round-trip, no min-max pass; fixed [0,2] quant f=min(4095,pd*2048)
// verified bit-exact in R8). D = R6 ballot rank-select (R8 atomics regressed).
// Recount: rank decomposes lt = C_below + lt_in (strict monotone quant);
// candidates append to a tiny LDS list, select among <=64 entries (guarded
// full-scan fallback). Phase E byte-identical p-strided (preserves loss
// summation order). Last-arriver completion (R5). ====
__global__ __launch_bounds__(NT) void k_all(
    const float* __restrict__ feat, const float* __restrict__ cent,
    const int* __restrict__ labels,
    float* __restrict__ lossv, float* __restrict__ wv,
    unsigned* __restrict__ flags, float* __restrict__ out)
{
  const int c = blockIdx.x;
  const int tid = threadIdx.x;
  const int wid = tid >> 6, lane = tid & 63;

  __shared__ int   gid_s[M_MAX];
  __shared__ int   mcount;
  __shared__ __align__(16) float tile[2 * TILE_F];     // 101376 B, double-buffered
  __shared__ __align__(16) float cvec[2][CK];
  // overlay on tile buffer 0 (used only after the last gram, which reads
  // buffer 1): Sl(P_MAX) + fidx(P_MAX ushort) = 6840 floats <= 12672.
  float*          Sl     = tile;
  unsigned short* fidx_s = (unsigned short*)(tile + P_MAX);
  __shared__ float selfs[M_MAX];
  __shared__ float ecs[M_MAX];
  __shared__ float cn_sh;
  __shared__ int   wcnt[NW * 64];
  __shared__ int   B0_sh, ex_sh, B1_sh, ex2_sh;
  __shared__ float thr_sh;
  __shared__ float lst[LCAP];
  __shared__ int   listn;
  __shared__ float redbuf[2 * NW];
  __shared__ int   last_sh;

  // ---- phase A: collect members of class c (int4 label loads) ----
  if (tid == 0) mcount = 0;
  __syncthreads();
  {
    const int4* lab4 = (const int4*)labels;
    for (int i = tid; i < B_ / 4; i += NT){
      int4 L = lab4[i];
      int base = i << 2;
      if (L.x == c){ int p = atomicAdd(&mcount, 1); if (p < M_MAX) gid_s[p] = base; }
      if (L.y == c){ int p = atomicAdd(&mcount, 1); if (p < M_MAX) gid_s[p] = base + 1; }
      if (L.z == c){ int p = atomicAdd(&mcount, 1); if (p < M_MAX) gid_s[p] = base + 2; }
      if (L.w == c){ int p = atomicAdd(&mcount, 1); if (p < M_MAX) gid_s[p] = base + 3; }
    }
  }
  __syncthreads();
  const int m = mcount;

  float lloss = 0.f, lw = 0.f;

  if (m >= 2 && m <= M_MAX){
    const int P = m * (m - 1) / 2;
    const int k0 = (P - 1) >> 1;
    const float wc = (float)m;
    const int nst = m * (CK / 4);

    // ---- unit setup: split-row 2x2 tiles + split-row ec units (R6) ----
    const int h    = (m + 1) >> 1;
    const int Upair = h * (h + 1) / 2;
    const int hec  = (m + 2) >> 1;
    const int U    = Upair + hec;

    int c0[LM2], c1[LM2], c2[LM2], c3[LM2];
    int tAv[LM2], tBv[LM2];
    float acc[LM2][4];
    int nlay = 0;
#pragma unroll
    for (int t = 0; t < LM2; ++t){
      acc[t][0] = acc[t][1] = acc[t][2] = acc[t][3] = 0.f;
      c0[t] = c1[t] = c2[t] = c3[t] = 0; tAv[t] = 0; tBv[t] = -3;
      int u = tid + t * NT;
      if (u < U){
        nlay = t + 1;
        if (u < Upair){
          int ta = 0;
          while ((ta + 1) * h - ((ta + 1) * ta) / 2 <= u) ++ta;
          int tb = ta + (u - (ta * h - (ta * (ta - 1)) / 2));
          c0[t] = ta; c1[t] = ta + h; c2[t] = tb; c3[t] = tb + h;
          tAv[t] = ta; tBv[t] = tb;
        } else {
          int g = u - Upair;
          int l1 = g + hec;
          c0[t] = g;
          c1[t] = (l1 == m) ? RC : ((l1 < m) ? l1 : 0);
          c2[t] = RC; c3[t] = RC;
          tAv[t] = g; tBv[t] = -1;
        }
      }
    }

    // ---- phase B: double-buffered staging; single barrier per chunk ----
    float4 pf[SPT];
    float4 cpf;
#pragma unroll
    for (int k = 0; k < SPT; ++k){
      int e = tid + k * NT;
      if (e < nst){
        int r = e >> 5, j = e & 31;
        pf[k] = ((const float4*)(feat + (size_t)gid_s[r] * D_))[j];
      }
    }
    if (tid < CK/4) cpf = ((const float4*)(cent + (size_t)c * D_))[tid];
#pragma unroll
    for (int k = 0; k < SPT; ++k){
      int e = tid + k * NT;
      if (e < nst){
        int r = e >> 5, j = e & 31;
        ((float4*)&tile[r * SROW])[j] = pf[k];
      }
    }
    if (tid < CK/4) ((float4*)cvec[0])[tid] = cpf;
    __syncthreads();

    for (int ch = 0; ch < NCH; ++ch){
      const int cur = ch & 1;
      if (ch + 1 < NCH){
        const int d0 = (ch + 1) * CK;
#pragma unroll
        for (int k = 0; k < SPT; ++k){
          int e = tid + k * NT;
          if (e < nst){
            int r = e >> 5, j = e & 31;
            pf[k] = ((const float4*)(feat + (size_t)gid_s[r] * D_ + d0))[j];
          }
        }
        if (tid < CK/4) cpf = ((const float4*)(cent + (size_t)c * D_ + d0))[tid];
      }
      {
        const float* tl = tile + cur * TILE_F;
        const float4* cv4 = (const float4*)cvec[cur];
#pragma unroll
        for (int t = 0; t < LM2; ++t){
          if (t < nlay){
            const float4* A0 = (c0[t] == RC) ? cv4 : (const float4*)&tl[c0[t] * SROW];
            const float4* A1 = (c1[t] == RC) ? cv4 : (const float4*)&tl[c1[t] * SROW];
            const float4* Bp0 = (c2[t] == RC) ? cv4 : (const float4*)&tl[c2[t] * SROW];
            const float4* Bp1 = (c3[t] == RC) ? cv4 : (const float4*)&tl[c3[t] * SROW];
            float s00 = 0.f, s01 = 0.f, s10 = 0.f, s11 = 0.f;
#pragma unroll 8
            for (int j = 0; j < CK/4; ++j){
              float4 a0 = A0[j], a1 = A1[j], b0 = Bp0[j], b1 = Bp1[j];
              s00 += dot4(a0, b0); s01 += dot4(a0, b1);
              s10 += dot4(a1, b0); s11 += dot4(a1, b1);
            }
            acc[t][0] += s00; acc[t][1] += s01;
            acc[t][2] += s10; acc[t][3] += s11;
          }
        }
      }
      if (ch + 1 < NCH){
        float* tn = tile + (cur ^ 1) * TILE_F;
#pragma unroll
        for (int k = 0; k < SPT; ++k){
          int e = tid + k * NT;
          if (e < nst){
            int r = e >> 5, j = e & 31;
            ((float4*)&tn[r * SROW])[j] = pf[k];
          }
        }
        if (tid < CK/4) ((float4*)cvec[cur ^ 1])[tid] = cpf;
      }
      __syncthreads();
    }

    // combine: owner-writes selfs/ecs/cn ONLY (pair dots stay in registers)
#pragma unroll
    for (int t = 0; t < LM2; ++t){
      if (t < nlay){
        if (tBv[t] == -1){
          int g = tAv[t], l1 = g + hec;
          ecs[g] = acc[t][0];
          if (l1 == m) cn_sh = acc[t][2];
          else if (l1 < m) ecs[l1] = acc[t][2];
        } else if (tBv[t] >= 0){
          const int ta = tAv[t], tb = tBv[t];
          const int a1 = ta + h;
          if (ta == tb){
            if (ta < m) selfs[ta] = acc[t][0];
            if (a1 < m) selfs[a1] = acc[t][3];
          }
        }
      }
    }
    __syncthreads();
    if (tid == 0) listn = 0;
    if (tid < m){
      float rn  = 1.f / fmaxf(sqrtf(selfs[tid]), 1e-12f);
      float cno = 1.f / fmaxf(sqrtf(cn_sh), 1e-12f);
      selfs[tid] = rn;
      ecs[tid] = ecs[tid] * rn * cno;
    }
    __syncthreads();

    // ---- registerized phase C: per-slot S/pd/f from acc; write Sl + fidx.
    // S = (acc*selfs[pa])*selfs[pb] — same left-assoc as R6 (mul commutative
    // => bit-identical). pd in [0,2] exactly; f = min(4095, pd*2048) is the
    // R8-verified monotone quantization. ----
    float pdq_[LM2][4];
    int   fq_[LM2][4];
#pragma unroll
    for (int t = 0; t < LM2; ++t){
#pragma unroll
      for (int s = 0; s < 4; ++s){ pdq_[t][s] = 0.f; fq_[t][s] = -1; }
      if (t < nlay && tBv[t] >= 0){
        const int ta = tAv[t], tb = tBv[t], a1 = ta + h, b1 = tb + h;
        const int  pa[4]  = { ta, ta, tb, a1 };
        const int  pb[4]  = { tb, b1, a1, b1 };
        const bool dif    = (ta != tb);
        const bool val[4] = { dif, b1 < m, dif && (a1 < m), dif && (a1 < m) && (b1 < m) };
#pragma unroll
        for (int s = 0; s < 4; ++s){
          if (val[s]){
            float S = acc[t][s] * selfs[pa[s]]; S *= selfs[pb[s]];
            float pd = 1.f - clamp1(S);
            int p = (pa[s] * (2*m - 1 - pa[s])) / 2 + (pb[s] - pa[s] - 1);
            Sl[p] = S;
            int f = min(4095, (int)(pd * 2048.f));
            fidx_s[p] = (unsigned short)f;
            pdq_[t][s] = pd; fq_[t][s] = f;
          }
        }
      }
    }
    __syncthreads();

    // ---- phase D: two-level ballot rank-select (R6 verbatim, fixed bins) ----
    const int nch = (P + NT - 1) / NT;
    int cl = 0;
    for (int t = 0; t < nch; ++t){
      int p = tid + t * NT;
      int bkt = -1;
      if (p < P) bkt = fidx_s[p] >> 6;
#pragma unroll
      for (int k = 0; k < 64; ++k){
        unsigned long long msk = __ballot(bkt == k);
        if (lane == k) cl += __popcll(msk);
      }
    }
    wcnt[wid*64 + lane] = cl;
    __syncthreads();
    if (tid < 64){
      int tot = 0;
#pragma unroll
      for (int w = 0; w < NW; ++w) tot += wcnt[w*64 + tid];
      int inc = tot;
#pragma unroll
      for (int o = 1; o < 64; o <<= 1){
        int v = __shfl_up(inc, o, 64);
        if (tid >= o) inc += v;
      }
      int excl = inc - tot;
      if (excl <= k0 && k0 < inc){ B0_sh = tid; ex_sh = excl; }
    }
    __syncthreads();
    const int Bsel0 = B0_sh;
    const int kt = k0 - ex_sh;
    cl = 0;
    for (int t = 0; t < nch; ++t){
      int p = tid + t * NT;
      int bkt = -1;
      if (p < P){
        int f = fidx_s[p];
        if ((f >> 6) == Bsel0) bkt = f & 63;
      }
#pragma unroll
      for (int k = 0; k < 64; ++k){
        unsigned long long msk = __ballot(bkt == k);
        if (lane == k) cl += __popcll(msk);
      }
    }
    wcnt[wid*64 + lane] = cl;
    __syncthreads();
    if (tid < 64){
      int tot = 0;
#pragma unroll
      for (int w = 0; w < NW; ++w) tot += wcnt[w*64 + tid];
      int inc = tot;
#pragma unroll
      for (int o = 1; o < 64; o <<= 1){
        int v = __shfl_up(inc, o, 64);
        if (tid >= o) inc += v;
      }
      int excl = inc - tot;
      if (excl <= kt && kt < inc){ B1_sh = tid; ex2_sh = excl; }
    }
    __syncthreads();
    const int fsel = (Bsel0 << 6) | B1_sh;
    const int ktf  = kt - ex2_sh;      // rank within the selected fine bin

    // candidates append from registers (each pair owned by exactly one slot)
#pragma unroll
    for (int t = 0; t < LM2; ++t){
#pragma unroll
      for (int s = 0; s < 4; ++s){
        if (fq_[t][s] == fsel){
          int ix = atomicAdd(&listn, 1);
          if (ix < LCAP) lst[ix] = pdq_[t][s];
        }
      }
    }
    __syncthreads();
    const int ln = listn;
    if (ln <= LCAP){
      // exact in-bin rank-select among <=LCAP candidates.
      // lt_global = C_below + lt_in; C_below = ex_sh + ex2_sh; k0-C_below = ktf.
      if (tid < ln){
        float pdp = lst[tid];
        int lt = 0, eq = 0;
        for (int j = 0; j < ln; ++j){
          float v = lst[j];
          lt += (v < pdp); eq += (v == pdp);
        }
        if (lt <= ktf && ktf < lt + eq) thr_sh = pdp;   // ties write same value
      }
    } else {
      // overflow fallback (unreachable for this data): R6-style full recount.
      for (int p = tid; p < P; p += NT){
        if (fidx_s[p] == (unsigned short)fsel){
          float pdp = 1.f - clamp1(Sl[p]);
          int lt = 0, eq = 0;
          for (int q = 0; q < P; ++q){
            float pdq = 1.f - clamp1(Sl[q]);
            lt += (pdq < pdp); eq += (pdq == pdp);
          }
          if (lt <= k0 && k0 < lt + eq) thr_sh = pdp;
        }
      }
    }
    __syncthreads();
    const float thr = thr_sh;

    // ---- phase E: p-strided, byte-identical summation order (reads Sl;
    // pd recomputed = 1-clamp1(S), identical bits to the old stored Pd) ----
    for (int p = tid; p < P; p += NT){
      float S = Sl[p];
      float pd = 1.f - clamp1(S);
      if (pd > thr){
        int a, b; decode_pair(p, m, &a, &b);
        int ga = gid_s[a], gb = gid_s[b];
        float ea = ecs[a], eb = ecs[b];
        int i, j; float eci, ecj;
        if (ga < gb){ i = ga; j = gb; eci = ea; ecj = eb; }
        else        { i = gb; j = ga; eci = eb; ecj = ea; }
        float r = rand_ij((unsigned)i * (unsigned)B_ + (unsigned)j);
        float omr = 1.f - r;
        float n2 = r * r + omr * omr + 2.f * r * omr * S;    // raw (unclipped) S
        float nrm = fmaxf(sqrtf(fmaxf(n2, 0.f)), 1e-12f);
        float dt = clamp1((r * eci + omr * ecj) / nrm);
        lloss += wc * (1.f - dt);
        lw += wc;
      }
    }
  } else if (m > M_MAX){
    // correctness-only fallback (impossible here: all m<=96, verified)
    int* mem = (int*)Sl;
    if (tid == 0) B0_sh = 0;
    __syncthreads();
    for (int i = tid; i < B_; i += NT)
      if (labels[i] == c){ int p = atomicAdd(&B0_sh, 1); mem[p] = i; }
    __syncthreads();
    const int P = m * (m - 1) / 2;
    const int k0 = (P - 1) >> 1;
    const float wc = (float)m;
    const float* cc = cent + (size_t)c * D_;
    const float cno = 1.f / fmaxf(sqrtf(dotg(cc, cc)), 1e-12f);
    for (int p = tid; p < P; p += NT){
      int a, b; decode_pair(p, m, &a, &b);
      float pdp = 1.f - clamp1(S_pair_g(feat, mem[a], mem[b]));
      int lt = 0, eq = 0;
      for (int q = 0; q < P; ++q){
        int a2, b2; decode_pair(q, m, &a2, &b2);
        float pdq = 1.f - clamp1(S_pair_g(feat, mem[a2], mem[b2]));
        lt += (pdq < pdp); eq += (pdq == pdp);
      }
      if (lt <= k0 && k0 < lt + eq) thr_sh = pdp;
    }
    __syncthreads();
    const float thr = thr_sh;
    for (int p = tid; p < P; p += NT){
      int a, b; decode_pair(p, m, &a, &b);
      int ga = mem[a], gb = mem[b];
      float S = S_pair_g(feat, ga, gb);
      float pd = 1.f - clamp1(S);
      if (pd > thr){
        if (ga > gb){ int t2 = ga; ga = gb; gb = t2; }
        const float* ra = feat + (size_t)ga * D_;
        const float* rb = feat + (size_t)gb * D_;
        float eci = dotg(ra, cc) / fmaxf(sqrtf(dotg(ra, ra)), 1e-12f) * cno;
        float ecj = dotg(rb, cc) / fmaxf(sqrtf(dotg(rb, rb)), 1e-12f) * cno;
        float r = rand_ij((unsigned)ga * (unsigned)B_ + (unsigned)gb);
        float omr = 1.f - r;
        float n2 = r * r + omr * omr + 2.f * r * omr * S;
        float nrm = fmaxf(sqrtf(fmaxf(n2, 0.f)), 1e-12f);
        float dt = clamp1((r * eci + omr * ecj) / nrm);
        lloss += wc * (1.f - dt);
        lw += wc;
      }
    }
  }
  // m < 2: contributes zeros

  // ---- phase F: last-arriver completion (R5). Publish partials (relaxed),
  // one acq_rel counter RMW, exit; the 128th arriver reduces. Init-agnostic:
  // any 128 consecutive olds contain exactly one ==127 (mod 128); stale
  // partial values are replay-invariant, so cross-launch reads are benign.
  lloss = wave_red(lloss); lw = wave_red(lw);
  if (lane == 0){ redbuf[wid] = lloss; redbuf[NW + wid] = lw; }
  __syncthreads();
  if (tid == 0){
    float tl = 0.f, tw = 0.f;
#pragma unroll
    for (int i = 0; i < NW; ++i){ tl += redbuf[i]; tw += redbuf[NW + i]; }
    __hip_atomic_store(&lossv[c], tl, __ATOMIC_RELAXED, __HIP_MEMORY_SCOPE_AGENT);
    __hip_atomic_store(&wv[c],   tw, __ATOMIC_RELAXED, __HIP_MEMORY_SCOPE_AGENT);
    unsigned old = __hip_atomic_fetch_add(&flags[0], 1u, __ATOMIC_ACQ_REL,
                                          __HIP_MEMORY_SCOPE_AGENT);
    last_sh = ((old & 127u) == 127u) ? 1 : 0;
  }
  __syncthreads();
  if (last_sh){
    float lv = 0.f, wvv = 0.f;
    if (tid < C_){
      lv  = __hip_atomic_load(&lossv[tid], __ATOMIC_RELAXED, __HIP_MEMORY_SCOPE_AGENT);
      wvv = __hip_atomic_load(&wv[tid],   __ATOMIC_RELAXED, __HIP_MEMORY_SCOPE_AGENT);
    }
    lv = wave_red(lv); wvv = wave_red(wvv);
    if (lane == 0){ redbuf[wid] = lv; redbuf[NW + wid] = wvv; }
    __syncthreads();
    if (tid == 0){
      float l = redbuf[0] + redbuf[1];
      float w = redbuf[NW] + redbuf[NW + 1];
      out[0] = (w > 0.f) ? (l / w) : 0.f;
    }
  }
}

extern "C" void kernel_launch(void* const* d_in, const int* in_sizes, int n_in,
                              void* d_out, int out_size, void* d_ws, size_t ws_size,
                              hipStream_t stream)
{
  const float* feat   = (const float*)d_in[0];
  const float* cent   = (const float*)d_in[1];
  const int*   labels = (const int*)d_in[2];
  // d_in[3] = cam_ids: unused by the reference computation.

  char* ws = (char*)d_ws;
  float*    lossv = (float*)(ws + 0);      // 128 floats
  float*    wvv   = (float*)(ws + 512);    // 128 floats
  unsigned* flags = (unsigned*)(ws + 1024);// [0] = arrival counter (mod-128 trigger)

  // single graph node: no memset needed (kernel is init-agnostic on ws)
  k_all<<<C_, NT, 0, stream>>>(feat, cent, labels, lossv, wvv, flags, (float*)d_out);
}